// Round 1
// baseline (204.964 us; speedup 1.0000x reference)
//
#include <hip/hip_runtime.h>

#define N_NODES 50000
#define N_EDGES 1200000
#define D_FEAT  64
#define HIDDEN  32

// ---------------------------------------------------------------------------
// Kernel 1: per-node precompute of layer 1.
//   P[node][j]      = sum_k x[node][k] * W1[k][j]        + b1[j]   (j in 0..31)
//   P[node][32 + j] = sum_k x[node][k] * W1[64 + k][j]             (j in 0..31)
// so that per edge:  h1 = relu(P[row][0:32] + P[col][32:64]).
// 4 nodes per 256-thread block; thread t handles (node = t/64, out = t%64).
// ---------------------------------------------------------------------------
__global__ __launch_bounds__(256) void precompute_P(
    const float* __restrict__ x, const float* __restrict__ W1,
    const float* __restrict__ b1, float* __restrict__ P)
{
    __shared__ float W1s[128 * 32];   // 16 KB
    const int tid = threadIdx.x;
    for (int i = tid; i < 128 * 32; i += 256) W1s[i] = W1[i];
    __syncthreads();

    const int node = blockIdx.x * 4 + (tid >> 6);
    const int j    = tid & 63;
    if (node >= N_NODES) return;

    const float* xr = x + node * D_FEAT;
    // effective W1 column base: top half rows for j<32, bottom half for j>=32
    const int base = (j < 32) ? j : (64 * 32 + (j - 32));
    float acc = (j < 32) ? b1[j] : 0.0f;
    #pragma unroll
    for (int k = 0; k < 64; ++k)
        acc = fmaf(xr[k], W1s[base + k * 32], acc);
    P[node * 64 + j] = acc;
}

// ---------------------------------------------------------------------------
// Kernel 2: per-edge MLP (layers 2,3) + scatter-add.
// One thread per edge. W2/b2/W3 staged in LDS (uniform-address broadcast).
// ---------------------------------------------------------------------------
__global__ __launch_bounds__(256) void edge_mlp_scatter(
    const int* __restrict__ row, const int* __restrict__ col,
    const float* __restrict__ u,
    const float* __restrict__ W2, const float* __restrict__ b2,
    const float* __restrict__ W3, const float* __restrict__ b3,
    const float* __restrict__ P, float* __restrict__ out)
{
    __shared__ float W2s[32 * 32];
    __shared__ float b2s[32];
    __shared__ float W3s[32];

    const int tid = threadIdx.x;
    for (int i = tid; i < 32 * 32; i += 256) W2s[i] = W2[i];
    if (tid < 32) { b2s[tid] = b2[tid]; W3s[tid] = W3[tid]; }
    __syncthreads();

    const int e = blockIdx.x * 256 + tid;
    if (e >= N_EDGES) return;

    const int r = row[e];
    const int c = col[e];

    const float4* p1 = (const float4*)(P + (size_t)r * 64);       // row-half (+b1)
    const float4* p2 = (const float4*)(P + (size_t)c * 64 + 32);  // col-half

    float h1[32];
    #pragma unroll
    for (int q = 0; q < 8; ++q) {
        float4 a = p1[q];
        float4 b = p2[q];
        h1[q * 4 + 0] = fmaxf(a.x + b.x, 0.0f);
        h1[q * 4 + 1] = fmaxf(a.y + b.y, 0.0f);
        h1[q * 4 + 2] = fmaxf(a.z + b.z, 0.0f);
        h1[q * 4 + 3] = fmaxf(a.w + b.w, 0.0f);
    }

    float w = b3[0];
    #pragma unroll
    for (int j = 0; j < 32; ++j) {
        float acc = b2s[j];
        #pragma unroll
        for (int k = 0; k < 32; ++k)
            acc = fmaf(h1[k], W2s[k * 32 + j], acc);
        w = fmaf(fmaxf(acc, 0.0f), W3s[j], w);
    }

    atomicAdd(out + r, w * u[c]);
}

extern "C" void kernel_launch(void* const* d_in, const int* in_sizes, int n_in,
                              void* d_out, int out_size, void* d_ws, size_t ws_size,
                              hipStream_t stream)
{
    const float* x    = (const float*)d_in[0];
    const int*   eidx = (const int*)  d_in[1];   // [2, E] int32
    const float* u    = (const float*)d_in[2];
    const float* W1   = (const float*)d_in[3];
    const float* b1   = (const float*)d_in[4];
    const float* W2   = (const float*)d_in[5];
    const float* b2   = (const float*)d_in[6];
    const float* W3   = (const float*)d_in[7];
    const float* b3   = (const float*)d_in[8];

    const int* row = eidx;
    const int* col = eidx + N_EDGES;

    float* P   = (float*)d_ws;                 // [N_NODES, 64] = 12.8 MB
    float* out = (float*)d_out;                // [N_NODES]

    // zero the output accumulator (harness poisons it with 0xAA)
    hipMemsetAsync(out, 0, N_NODES * sizeof(float), stream);

    // layer-1 precompute per node
    precompute_P<<<(N_NODES + 3) / 4, 256, 0, stream>>>(x, W1, b1, P);

    // per-edge MLP + scatter
    edge_mlp_scatter<<<(N_EDGES + 255) / 256, 256, 0, stream>>>(
        row, col, u, W2, b2, W3, b3, P, out);
}

// Round 2
// 182.543 us; speedup vs baseline: 1.1228x; 1.1228x over previous
//
#include <hip/hip_runtime.h>
#include <hip/hip_bf16.h>

#define N_NODES 50000
#define N_EDGES 1200000
#define D_FEAT  64
#define HIDDEN  32

typedef __attribute__((ext_vector_type(8))) short short8;   // 8 bf16 = 4 VGPRs
typedef __attribute__((ext_vector_type(4))) float floatx4;  // MFMA acc

// round-to-nearest-even fp32 -> bf16
__device__ __forceinline__ unsigned short f32_to_bf16(float f) {
    unsigned int u = __float_as_uint(f);
    unsigned int r = u + 0x7FFFu + ((u >> 16) & 1u);
    return (unsigned short)(r >> 16);
}
__device__ __forceinline__ float bf16_to_f32(unsigned short s) {
    return __uint_as_float(((unsigned int)s) << 16);
}

// ---------------------------------------------------------------------------
// Kernel 1: per-node layer-1 precompute (fp32 math, bf16 output).
//   P[node][j]      = x[node] . W1[0:64][j]  + b1[j]   (j in 0..31)
//   P[node][32 + j] = x[node] . W1[64:128][j]          (j in 0..31)
// Grid-stride over node-groups so W1 is staged into LDS only gridDim times.
// ---------------------------------------------------------------------------
__global__ __launch_bounds__(256) void precompute_P(
    const float* __restrict__ x, const float* __restrict__ W1,
    const float* __restrict__ b1, unsigned short* __restrict__ P)
{
    __shared__ float W1s[128 * 32];   // 16 KB
    const int tid = threadIdx.x;
    for (int i = tid; i < 128 * 32; i += 256) W1s[i] = W1[i];
    __syncthreads();

    const int j    = tid & 63;
    const int sub  = tid >> 6;                      // 0..3 node within group
    const int base = (j < 32) ? j : (64 * 32 + (j - 32));
    const float bias = (j < 32) ? b1[j] : 0.0f;

    const int ngroups = (N_NODES + 3) / 4;
    for (int g = blockIdx.x; g < ngroups; g += gridDim.x) {
        const int node = g * 4 + sub;
        if (node >= N_NODES) continue;
        const float* xr = x + node * D_FEAT;
        float acc = bias;
        #pragma unroll
        for (int k = 0; k < 64; ++k)
            acc = fmaf(xr[k], W1s[base + k * 32], acc);
        P[node * 64 + j] = f32_to_bf16(acc);
    }
}

// ---------------------------------------------------------------------------
// Kernel 2: per-edge layers 2+3 via MFMA + scatter-add.
// One wave = 2 tiles of 16 edges. Lane (q = lane>>4, m = lane&15):
//   A-frag: h1[m][k], k = q*8..q*8+7, gathered straight from P (bf16).
//   B-frag: W2[k][n], n = lane&15 (two frags for n and n+16), loaded once.
//   C init = b2[n]; D: row(edge) = q*4+reg, col(j) = n.
//   layer 3: t = relu(d0)*W3[n] + relu(d1)*W3[n+16], reduce over 16 lanes.
// No LDS at all.
// ---------------------------------------------------------------------------
__global__ __launch_bounds__(256) void edge_mlp_mfma(
    const int* __restrict__ row, const int* __restrict__ col,
    const float* __restrict__ u,
    const float* __restrict__ W2, const float* __restrict__ b2,
    const float* __restrict__ W3, const float* __restrict__ b3,
    const unsigned short* __restrict__ P, float* __restrict__ out)
{
    const int lane = threadIdx.x & 63;
    const int n = lane & 15;
    const int q = lane >> 4;

    // B fragments (loaded once; L1/L2 broadcast)
    short8 bf0, bf1;
    #pragma unroll
    for (int i = 0; i < 8; ++i) {
        const int k = q * 8 + i;
        bf0[i] = (short)f32_to_bf16(W2[k * 32 + n]);
        bf1[i] = (short)f32_to_bf16(W2[k * 32 + n + 16]);
    }
    const float w3n0 = W3[n], w3n1 = W3[n + 16];
    const float b2n0 = b2[n], b2n1 = b2[n + 16];
    const float bias3 = b3[0];

    const int wave = (blockIdx.x * 256 + (int)threadIdx.x) >> 6;  // 0..37499
    const int base0 = wave * 32;                                   // 2 tiles

    // --- gather phase (both tiles issued together for ILP) ---
    int rI[2], cI[2];
    short8 v1[2], v2[2];
    #pragma unroll
    for (int t = 0; t < 2; ++t) {
        const int e = base0 + t * 16 + n;
        rI[t] = row[e];
        cI[t] = col[e];
    }
    #pragma unroll
    for (int t = 0; t < 2; ++t) {
        v1[t] = *(const short8*)(P + (size_t)rI[t] * 64 + q * 8);
        v2[t] = *(const short8*)(P + (size_t)cI[t] * 64 + 32 + q * 8);
    }

    // --- compute phase ---
    float tr[2][4];
    #pragma unroll
    for (int t = 0; t < 2; ++t) {
        short8 a;
        #pragma unroll
        for (int i = 0; i < 8; ++i) {
            const float f1 = bf16_to_f32((unsigned short)v1[t][i]);
            const float f2 = bf16_to_f32((unsigned short)v2[t][i]);
            a[i] = (short)f32_to_bf16(fmaxf(f1 + f2, 0.0f));
        }
        floatx4 d0 = {b2n0, b2n0, b2n0, b2n0};
        floatx4 d1 = {b2n1, b2n1, b2n1, b2n1};
        d0 = __builtin_amdgcn_mfma_f32_16x16x32_bf16(a, bf0, d0, 0, 0, 0);
        d1 = __builtin_amdgcn_mfma_f32_16x16x32_bf16(a, bf1, d1, 0, 0, 0);
        #pragma unroll
        for (int r = 0; r < 4; ++r)
            tr[t][r] = fmaxf(d0[r], 0.0f) * w3n0 + fmaxf(d1[r], 0.0f) * w3n1;
    }

    // reduce over the 16 lanes of each quad (j dimension)
    #pragma unroll
    for (int mask = 1; mask < 16; mask <<= 1) {
        #pragma unroll
        for (int t = 0; t < 2; ++t)
            #pragma unroll
            for (int r = 0; r < 4; ++r)
                tr[t][r] += __shfl_xor(tr[t][r], mask, 64);
    }

    if (n == 0) {
        #pragma unroll
        for (int t = 0; t < 2; ++t) {
            #pragma unroll
            for (int r = 0; r < 4; ++r) {
                const int e = base0 + t * 16 + q * 4 + r;
                const float w = tr[t][r] + bias3;
                atomicAdd(out + row[e], w * u[col[e]]);
            }
        }
    }
}

extern "C" void kernel_launch(void* const* d_in, const int* in_sizes, int n_in,
                              void* d_out, int out_size, void* d_ws, size_t ws_size,
                              hipStream_t stream)
{
    const float* x    = (const float*)d_in[0];
    const int*   eidx = (const int*)  d_in[1];   // [2, E] int32
    const float* u    = (const float*)d_in[2];
    const float* W1   = (const float*)d_in[3];
    const float* b1   = (const float*)d_in[4];
    const float* W2   = (const float*)d_in[5];
    const float* b2   = (const float*)d_in[6];
    const float* W3   = (const float*)d_in[7];
    const float* b3   = (const float*)d_in[8];

    const int* row = eidx;
    const int* col = eidx + N_EDGES;

    unsigned short* P = (unsigned short*)d_ws;   // [N_NODES, 64] bf16 = 6.4 MB
    float* out = (float*)d_out;                  // [N_NODES]

    hipMemsetAsync(out, 0, N_NODES * sizeof(float), stream);

    precompute_P<<<1024, 256, 0, stream>>>(x, W1, b1, P);

    // 1.2M edges / (4 waves * 32 edges per wave) = 9375 blocks
    edge_mlp_mfma<<<N_EDGES / 128, 256, 0, stream>>>(
        row, col, u, W2, b2, W3, b3, P, out);
}

// Round 3
// 160.487 us; speedup vs baseline: 1.2771x; 1.1374x over previous
//
#include <hip/hip_runtime.h>
#include <hip/hip_bf16.h>

#define N_NODES 50000
#define N_EDGES 1200000
#define D_FEAT  64
#define HIDDEN  32
#define N_TILES (N_NODES / 16)   // 3125, exact

typedef __attribute__((ext_vector_type(8))) short short8;   // 8 bf16 = 4 VGPRs
typedef __attribute__((ext_vector_type(4))) float floatx4;  // MFMA acc

__device__ __forceinline__ unsigned short f32_to_bf16(float f) {
    unsigned int u = __float_as_uint(f);
    unsigned int r = u + 0x7FFFu + ((u >> 16) & 1u);
    return (unsigned short)(r >> 16);
}
__device__ __forceinline__ float bf16_to_f32(unsigned short s) {
    return __uint_as_float(((unsigned int)s) << 16);
}

// ---------------------------------------------------------------------------
// Kernel 1: layer-1 precompute as an MFMA GEMM.  P[50000][64] bf16:
//   P[i][j]    = x[i] . W1[0:64][j]  + b1[j]   (j<32)   -> "row half"
//   P[i][32+j] = x[i] . W1[64:128][j]          (j<32)   -> "col half"
// One wave per 16-node tile. A-frags from coalesced float4 loads of x,
// W1 held in 8 B-fragments per lane (no LDS). b1 seeds the accumulator.
// ---------------------------------------------------------------------------
__global__ __launch_bounds__(256) void precompute_P_mfma(
    const float* __restrict__ x, const float* __restrict__ W1,
    const float* __restrict__ b1, unsigned short* __restrict__ P)
{
    const int lane = threadIdx.x & 63;
    const int n = lane & 15;
    const int q = lane >> 4;

    // B-fragments: bf[G][h][i] = W_eff[k = h*32 + q*8 + i][j = n + 16G]
    // W_eff[k][j] = (j<32) ? W1[k][j] : W1[64+k][j-32]
    short8 bf[4][2];
    #pragma unroll
    for (int G = 0; G < 4; ++G) {
        #pragma unroll
        for (int h = 0; h < 2; ++h) {
            #pragma unroll
            for (int i = 0; i < 8; ++i) {
                const int k = h * 32 + q * 8 + i;
                const int j = n + 16 * G;
                const float w = (G < 2) ? W1[k * 32 + j]
                                        : W1[(64 + k) * 32 + (j - 32)];
                bf[G][h][i] = (short)f32_to_bf16(w);
            }
        }
    }
    const float binit[4] = { b1[n], b1[n + 16], 0.0f, 0.0f };

    const int tile = blockIdx.x * 4 + (int)(threadIdx.x >> 6);
    if (tile >= N_TILES) return;
    const int node = tile * 16 + n;

    // A-fragments: a0 covers k=0..31 (x cols 0..31), a1 covers k=32..63
    const float4* xr = (const float4*)(x + (size_t)node * 64 + q * 8);
    float4 xa = xr[0], xb = xr[1];
    const float4* xr2 = (const float4*)(x + (size_t)node * 64 + 32 + q * 8);
    float4 xc = xr2[0], xd = xr2[1];

    short8 a0, a1;
    a0[0] = (short)f32_to_bf16(xa.x); a0[1] = (short)f32_to_bf16(xa.y);
    a0[2] = (short)f32_to_bf16(xa.z); a0[3] = (short)f32_to_bf16(xa.w);
    a0[4] = (short)f32_to_bf16(xb.x); a0[5] = (short)f32_to_bf16(xb.y);
    a0[6] = (short)f32_to_bf16(xb.z); a0[7] = (short)f32_to_bf16(xb.w);
    a1[0] = (short)f32_to_bf16(xc.x); a1[1] = (short)f32_to_bf16(xc.y);
    a1[2] = (short)f32_to_bf16(xc.z); a1[3] = (short)f32_to_bf16(xc.w);
    a1[4] = (short)f32_to_bf16(xd.x); a1[5] = (short)f32_to_bf16(xd.y);
    a1[6] = (short)f32_to_bf16(xd.z); a1[7] = (short)f32_to_bf16(xd.w);

    #pragma unroll
    for (int G = 0; G < 4; ++G) {
        floatx4 acc = { binit[G], binit[G], binit[G], binit[G] };
        acc = __builtin_amdgcn_mfma_f32_16x16x32_bf16(a0, bf[G][0], acc, 0, 0, 0);
        acc = __builtin_amdgcn_mfma_f32_16x16x32_bf16(a1, bf[G][1], acc, 0, 0, 0);
        // D: row = q*4 + r (node within tile), col = n (+16G)
        #pragma unroll
        for (int r = 0; r < 4; ++r)
            P[(size_t)(tile * 16 + q * 4 + r) * 64 + n + 16 * G] =
                f32_to_bf16(acc[r]);
    }
}

// ---------------------------------------------------------------------------
// Kernel 2: per-edge layers 2+3 via MFMA + scatter-add.
// Persistent grid-stride waves; each wave iterates 32-edge chunks (2 MFMA
// tiles). W2/W3/b2 fragment setup paid once per wave, amortized ~9x.
// Atomic phase: lane (q, n<8) locally owns the reduced sum for edge
// base0 + 16*(n>>2) + 4q + (n&3)  ->  no cross-lane move, 32 active lanes.
// ---------------------------------------------------------------------------
__global__ __launch_bounds__(256) void edge_mlp_mfma(
    const int* __restrict__ row, const int* __restrict__ col,
    const float* __restrict__ u,
    const float* __restrict__ W2, const float* __restrict__ b2,
    const float* __restrict__ W3, const float* __restrict__ b3,
    const unsigned short* __restrict__ P, float* __restrict__ out)
{
    const int lane = threadIdx.x & 63;
    const int n = lane & 15;
    const int q = lane >> 4;

    // B fragments for layer 2 (held in registers for the whole kernel)
    short8 bf0, bf1;
    #pragma unroll
    for (int i = 0; i < 8; ++i) {
        const int k = q * 8 + i;
        bf0[i] = (short)f32_to_bf16(W2[k * 32 + n]);
        bf1[i] = (short)f32_to_bf16(W2[k * 32 + n + 16]);
    }
    const float w3n0 = W3[n], w3n1 = W3[n + 16];
    const float b2n0 = b2[n], b2n1 = b2[n + 16];
    const float bias3 = b3[0];

    const int wave   = (blockIdx.x * 256 + (int)threadIdx.x) >> 6;
    const int nwaves = gridDim.x * 4;
    const int nchunks = N_EDGES / 32;   // 37500, exact

    for (int ch = wave; ch < nchunks; ch += nwaves) {
        const int base0 = ch * 32;

        // ---- index loads (gather phase) ----
        int rI[2], cI[2];
        #pragma unroll
        for (int t = 0; t < 2; ++t) {
            const int e = base0 + t * 16 + n;
            rI[t] = row[e];
            cI[t] = col[e];
        }
        // ---- atomic-phase edge data, issued early to hide latency ----
        int r2 = 0; float u2 = 0.0f;
        if (n < 8) {
            const int e2 = base0 + 16 * (n >> 2) + 4 * q + (n & 3);
            r2 = row[e2];
            u2 = u[col[e2]];
        }
        // ---- P gathers ----
        short8 v1[2], v2[2];
        #pragma unroll
        for (int t = 0; t < 2; ++t) {
            v1[t] = *(const short8*)(P + (size_t)rI[t] * 64 + q * 8);
            v2[t] = *(const short8*)(P + (size_t)cI[t] * 64 + 32 + q * 8);
        }

        // ---- compute ----
        float tr[2][4];
        #pragma unroll
        for (int t = 0; t < 2; ++t) {
            short8 a;
            #pragma unroll
            for (int i = 0; i < 8; ++i) {
                const float f1 = bf16_to_f32((unsigned short)v1[t][i]);
                const float f2 = bf16_to_f32((unsigned short)v2[t][i]);
                a[i] = (short)f32_to_bf16(fmaxf(f1 + f2, 0.0f));
            }
            floatx4 d0 = {b2n0, b2n0, b2n0, b2n0};
            floatx4 d1 = {b2n1, b2n1, b2n1, b2n1};
            d0 = __builtin_amdgcn_mfma_f32_16x16x32_bf16(a, bf0, d0, 0, 0, 0);
            d1 = __builtin_amdgcn_mfma_f32_16x16x32_bf16(a, bf1, d1, 0, 0, 0);
            #pragma unroll
            for (int r = 0; r < 4; ++r)
                tr[t][r] = fmaxf(d0[r], 0.0f) * w3n0 + fmaxf(d1[r], 0.0f) * w3n1;
        }

        // reduce over the 16 lanes of each quad (j dimension)
        #pragma unroll
        for (int mask = 1; mask < 16; mask <<= 1) {
            #pragma unroll
            for (int t = 0; t < 2; ++t)
                #pragma unroll
                for (int r = 0; r < 4; ++r)
                    tr[t][r] += __shfl_xor(tr[t][r], mask, 64);
        }

        // ---- scatter: lane (q, n<8) owns edge base0 + 16*(n>>2)+4q+(n&3),
        //      value tr[n>>2][n&3], selected with 7 cndmasks ----
        if (n < 8) {
            const float va0 = (n & 4) ? tr[1][0] : tr[0][0];
            const float va1 = (n & 4) ? tr[1][1] : tr[0][1];
            const float va2 = (n & 4) ? tr[1][2] : tr[0][2];
            const float va3 = (n & 4) ? tr[1][3] : tr[0][3];
            const float vb0 = (n & 2) ? va2 : va0;
            const float vb1 = (n & 2) ? va3 : va1;
            const float v   = (n & 1) ? vb1 : vb0;
            atomicAdd(out + r2, (v + bias3) * u2);
        }
    }
}

extern "C" void kernel_launch(void* const* d_in, const int* in_sizes, int n_in,
                              void* d_out, int out_size, void* d_ws, size_t ws_size,
                              hipStream_t stream)
{
    const float* x    = (const float*)d_in[0];
    const int*   eidx = (const int*)  d_in[1];   // [2, E] int32
    const float* u    = (const float*)d_in[2];
    const float* W1   = (const float*)d_in[3];
    const float* b1   = (const float*)d_in[4];
    const float* W2   = (const float*)d_in[5];
    const float* b2   = (const float*)d_in[6];
    const float* W3   = (const float*)d_in[7];
    const float* b3   = (const float*)d_in[8];

    const int* row = eidx;
    const int* col = eidx + N_EDGES;

    unsigned short* P = (unsigned short*)d_ws;   // [N_NODES, 64] bf16 = 6.4 MB
    float* out = (float*)d_out;                  // [N_NODES]

    hipMemsetAsync(out, 0, N_NODES * sizeof(float), stream);

    // 3125 tiles, 4 waves/block -> 782 blocks
    precompute_P_mfma<<<(N_TILES + 3) / 4, 256, 0, stream>>>(x, W1, b1, P);

    // persistent waves: 1024 blocks * 4 waves = 4096 waves, ~9 chunks each
    edge_mlp_mfma<<<1024, 256, 0, stream>>>(
        row, col, u, W2, b2, W3, b3, P, out);
}

// Round 4
// 153.053 us; speedup vs baseline: 1.3392x; 1.0486x over previous
//
#include <hip/hip_runtime.h>

#define N_NODES 50000
#define N_EDGES 1200000
#define N_TILES (N_NODES / 16)   // 3125, exact
#define N_REP   16               // replicated atomic accumulators
#define REP_STRIDE 50064         // floats; 50064*4 = 64*3129 (odd #lines)
#define W1T_STRIDE 72            // bf16 elems per j-row in LDS (16B aligned)

typedef __attribute__((ext_vector_type(8))) short short8;   // 8 bf16
typedef __attribute__((ext_vector_type(4))) float floatx4;  // MFMA acc

__device__ __forceinline__ unsigned short f32_to_bf16(float f) {
    unsigned int u = __float_as_uint(f);
    unsigned int r = u + 0x7FFFu + ((u >> 16) & 1u);
    return (unsigned short)(r >> 16);
}
__device__ __forceinline__ float bf16_to_f32(unsigned short s) {
    return __uint_as_float(((unsigned int)s) << 16);
}
__device__ __forceinline__ unsigned int pack_bf16x2(float lo, float hi) {
    return (unsigned int)f32_to_bf16(lo) | ((unsigned int)f32_to_bf16(hi) << 16);
}

// ---------------------------------------------------------------------------
// Kernel 1: layer-1 precompute as MFMA GEMM, all memory ops coalesced.
// P layout per node = 64 bf16 (128 B):
//   half1 (ushort 0..31):  position p = n*2+g  holds  x.W1_top[n+16g] + b1   (P1)
//   half2 (ushort 32..63): position p = n*2+g  holds  x.W1_bot[n+16g]        (P2)
// W1 staged once per block into LDS, transposed+bf16: W1t[j][k], j=0..63.
// B-frags = 8 ds_read_b128 per wave. P stores = 8 coalesced dword stores/tile.
// ---------------------------------------------------------------------------
__global__ __launch_bounds__(256) void precompute_P_mfma(
    const float* __restrict__ x, const float* __restrict__ W1,
    const float* __restrict__ b1, unsigned short* __restrict__ P)
{
    __shared__ unsigned short W1t[64 * W1T_STRIDE];   // 9216 B
    const int tid = threadIdx.x;
    // W1 flat [128][32]: rows 0..63 = top (j=jp), rows 64..127 = bottom (j=jp+32)
    for (int e = tid; e < 128 * 32; e += 256) {
        const int kp = e >> 5, jp = e & 31;
        const int k = kp & 63;
        const int j = (kp < 64) ? jp : jp + 32;
        W1t[j * W1T_STRIDE + k] = f32_to_bf16(W1[e]);
    }
    __syncthreads();

    const int lane = tid & 63;
    const int n = lane & 15;
    const int q = lane >> 4;

    // B-frags: bf[G][h][i] = W_eff[k = h*32 + q*8 + i][j = n + 16G]
    short8 bf[4][2];
    #pragma unroll
    for (int G = 0; G < 4; ++G)
        #pragma unroll
        for (int h = 0; h < 2; ++h)
            bf[G][h] = *(const short8*)&W1t[(n + 16 * G) * W1T_STRIDE + h * 32 + q * 8];

    const float bias0 = b1[n], bias1 = b1[n + 16];

    unsigned int* P32 = (unsigned int*)P;   // node row = 32 dwords

    const int wid0   = blockIdx.x * 4 + (tid >> 6);
    const int stride = gridDim.x * 4;
    for (int tile = wid0; tile < N_TILES; tile += stride) {
        const int node = tile * 16 + n;
        const float4* xp  = (const float4*)(x + (size_t)node * 64 + q * 8);
        const float4 xa = xp[0], xb = xp[1];
        const float4* xp2 = (const float4*)(x + (size_t)node * 64 + 32 + q * 8);
        const float4 xc = xp2[0], xd = xp2[1];

        short8 a0, a1;
        a0[0] = (short)f32_to_bf16(xa.x); a0[1] = (short)f32_to_bf16(xa.y);
        a0[2] = (short)f32_to_bf16(xa.z); a0[3] = (short)f32_to_bf16(xa.w);
        a0[4] = (short)f32_to_bf16(xb.x); a0[5] = (short)f32_to_bf16(xb.y);
        a0[6] = (short)f32_to_bf16(xb.z); a0[7] = (short)f32_to_bf16(xb.w);
        a1[0] = (short)f32_to_bf16(xc.x); a1[1] = (short)f32_to_bf16(xc.y);
        a1[2] = (short)f32_to_bf16(xc.z); a1[3] = (short)f32_to_bf16(xc.w);
        a1[4] = (short)f32_to_bf16(xd.x); a1[5] = (short)f32_to_bf16(xd.y);
        a1[6] = (short)f32_to_bf16(xd.z); a1[7] = (short)f32_to_bf16(xd.w);

        floatx4 acc[4];
        #pragma unroll
        for (int G = 0; G < 4; ++G) {
            const float bi = (G == 0) ? bias0 : (G == 1) ? bias1 : 0.0f;
            acc[G] = (floatx4){bi, bi, bi, bi};
            acc[G] = __builtin_amdgcn_mfma_f32_16x16x32_bf16(a0, bf[G][0], acc[G], 0, 0, 0);
            acc[G] = __builtin_amdgcn_mfma_f32_16x16x32_bf16(a1, bf[G][1], acc[G], 0, 0, 0);
        }
        // D: row(node) = q*4+r, col j = n (+16G). Coalesced dword stores.
        #pragma unroll
        for (int r = 0; r < 4; ++r) {
            const int nr = tile * 16 + q * 4 + r;
            P32[(size_t)nr * 32 + n]      = pack_bf16x2(acc[0][r], acc[1][r]);
            P32[(size_t)nr * 32 + 16 + n] = pack_bf16x2(acc[2][r], acc[3][r]);
        }
    }
}

// ---------------------------------------------------------------------------
// Kernel 2: per-edge layers 2+3 via MFMA + replicated scatter-add.
// P positions hold permuted features: A-frag slot (q,i) = feature
// F(q,i) = 4q + (i>>1) + 16(i&1); W2/W3 B-frags loaded with the same F.
// Atomics go to replica (wave & 15) to cut same-line contention 16x.
// ---------------------------------------------------------------------------
__global__ __launch_bounds__(256) void edge_mlp_mfma(
    const int* __restrict__ row, const int* __restrict__ col,
    const float* __restrict__ u,
    const float* __restrict__ W2, const float* __restrict__ b2,
    const float* __restrict__ W3, const float* __restrict__ b3,
    const unsigned short* __restrict__ P, float* __restrict__ rep)
{
    const int lane = threadIdx.x & 63;
    const int n = lane & 15;
    const int q = lane >> 4;

    short8 bf0, bf1;
    #pragma unroll
    for (int i = 0; i < 8; ++i) {
        const int F = q * 4 + (i >> 1) + 16 * (i & 1);   // feature in slot (q,i)
        bf0[i] = (short)f32_to_bf16(W2[F * 32 + n]);
        bf1[i] = (short)f32_to_bf16(W2[F * 32 + n + 16]);
    }
    const float w3n0 = W3[n], w3n1 = W3[n + 16];
    const float b2n0 = b2[n], b2n1 = b2[n + 16];
    const float bias3 = b3[0];

    const int wave   = (blockIdx.x * 256 + (int)threadIdx.x) >> 6;
    const int nwaves = gridDim.x * 4;
    const int nchunks = N_EDGES / 32;   // 37500, exact
    float* myrep = rep + (size_t)(wave & (N_REP - 1)) * REP_STRIDE;

    for (int ch = wave; ch < nchunks; ch += nwaves) {
        const int base0 = ch * 32;

        int rI[2], cI[2];
        #pragma unroll
        for (int t = 0; t < 2; ++t) {
            const int e = base0 + t * 16 + n;
            rI[t] = row[e];
            cI[t] = col[e];
        }
        int r2 = 0; float u2 = 0.0f;
        if (n < 8) {
            const int e2 = base0 + 16 * (n >> 2) + 4 * q + (n & 3);
            r2 = row[e2];
            u2 = u[col[e2]];
        }
        short8 v1[2], v2[2];
        #pragma unroll
        for (int t = 0; t < 2; ++t) {
            v1[t] = *(const short8*)(P + (size_t)rI[t] * 64 + q * 8);
            v2[t] = *(const short8*)(P + (size_t)cI[t] * 64 + 32 + q * 8);
        }

        float tr[2][4];
        #pragma unroll
        for (int t = 0; t < 2; ++t) {
            short8 a;
            #pragma unroll
            for (int i = 0; i < 8; ++i) {
                const float f1 = bf16_to_f32((unsigned short)v1[t][i]);
                const float f2 = bf16_to_f32((unsigned short)v2[t][i]);
                a[i] = (short)f32_to_bf16(fmaxf(f1 + f2, 0.0f));
            }
            floatx4 d0 = {b2n0, b2n0, b2n0, b2n0};
            floatx4 d1 = {b2n1, b2n1, b2n1, b2n1};
            d0 = __builtin_amdgcn_mfma_f32_16x16x32_bf16(a, bf0, d0, 0, 0, 0);
            d1 = __builtin_amdgcn_mfma_f32_16x16x32_bf16(a, bf1, d1, 0, 0, 0);
            #pragma unroll
            for (int r = 0; r < 4; ++r)
                tr[t][r] = fmaxf(d0[r], 0.0f) * w3n0 + fmaxf(d1[r], 0.0f) * w3n1;
        }

        #pragma unroll
        for (int mask = 1; mask < 16; mask <<= 1) {
            #pragma unroll
            for (int t = 0; t < 2; ++t)
                #pragma unroll
                for (int r = 0; r < 4; ++r)
                    tr[t][r] += __shfl_xor(tr[t][r], mask, 64);
        }

        if (n < 8) {
            const float va0 = (n & 4) ? tr[1][0] : tr[0][0];
            const float va1 = (n & 4) ? tr[1][1] : tr[0][1];
            const float va2 = (n & 4) ? tr[1][2] : tr[0][2];
            const float va3 = (n & 4) ? tr[1][3] : tr[0][3];
            const float vb0 = (n & 2) ? va2 : va0;
            const float vb1 = (n & 2) ? va3 : va1;
            const float v   = (n & 1) ? vb1 : vb0;
            atomicAdd(myrep + r2, (v + bias3) * u2);
        }
    }
}

// ---------------------------------------------------------------------------
// Kernel 3: sum the 16 replicas into the output.
// ---------------------------------------------------------------------------
__global__ __launch_bounds__(256) void reduce_out(
    const float* __restrict__ rep, float* __restrict__ out)
{
    const int i = blockIdx.x * 256 + (int)threadIdx.x;
    if (i < N_NODES) {
        float s = 0.0f;
        #pragma unroll
        for (int r = 0; r < N_REP; ++r)
            s += rep[(size_t)r * REP_STRIDE + i];
        out[i] = s;
    }
}

extern "C" void kernel_launch(void* const* d_in, const int* in_sizes, int n_in,
                              void* d_out, int out_size, void* d_ws, size_t ws_size,
                              hipStream_t stream)
{
    const float* x    = (const float*)d_in[0];
    const int*   eidx = (const int*)  d_in[1];   // [2, E] int32
    const float* u    = (const float*)d_in[2];
    const float* W1   = (const float*)d_in[3];
    const float* b1   = (const float*)d_in[4];
    const float* W2   = (const float*)d_in[5];
    const float* b2   = (const float*)d_in[6];
    const float* W3   = (const float*)d_in[7];
    const float* b3   = (const float*)d_in[8];

    const int* row = eidx;
    const int* col = eidx + N_EDGES;

    unsigned short* P = (unsigned short*)d_ws;                   // 6.40 MB
    float* rep = (float*)((char*)d_ws + (size_t)N_NODES * 128);  // 3.20 MB
    float* out = (float*)d_out;

    hipMemsetAsync(rep, 0, (size_t)N_REP * REP_STRIDE * sizeof(float), stream);

    precompute_P_mfma<<<512, 256, 0, stream>>>(x, W1, b1, P);

    edge_mlp_mfma<<<1024, 256, 0, stream>>>(
        row, col, u, W2, b2, W3, b3, P, rep);

    reduce_out<<<(N_NODES + 255) / 256, 256, 0, stream>>>(rep, out);
}